// Round 2
// baseline (816.424 us; speedup 1.0000x reference)
//
#include <hip/hip_runtime.h>

// ---------------------------------------------------------------------------
// SelfAttention block-sparse value aggregation, fully fused, bf16 MFMA.
// B=8, H=W=128, E=256, VD=256, nh=8, vhd=32, bs=8 (bs2=64), topk=16.
// One workgroup (256 thr = 4 waves) per (batch, block) tile; 2048 WGs.
// R2: LDS 52KB->40KB (4 WG/CU), K-pad via register-zeroed A-frags,
//     phase-2 A-frag hoist + double-buffered aw prefetch, launch_bounds(256,4).
// R3: pin amdgpu_waves_per_eu(4,4). Occupancy is LDS-capped at 4 WG/CU
//     (40 KB), but the allocator was targeting 8 waves/EU -> 64 VGPRs ->
//     the phase-2 double-buffer (acc32+pb32+nb32 ~ 110 live) spilled to
//     scratch (~224 MB of writeback showed up in WRITE_SIZE) and loads
//     serialized (MfmaUtil/VALUBusy/HBM all <25%). Budget 128 VGPRs so the
//     prefetch the source expresses actually lives in registers.
// R4: identical resubmit — R3 bench failed on container acquisition (infra),
//     not on the kernel; the regalloc experiment still needs its clean run.
// LDS: XPT[256 cols][80 tokens] bf16 (stride 160B); per-head ATT region
// (5120B, stride 80B) aliases exactly that head's 32 XPT rows, written by the
// same wave after its reads complete -> single __syncthreads() in kernel.
// ---------------------------------------------------------------------------

typedef __attribute__((ext_vector_type(4))) float   f32x4;
typedef __attribute__((ext_vector_type(8))) __bf16  bf16x8;
typedef __attribute__((ext_vector_type(4))) __bf16  bf16x4;

#define XPT_STRIDE 160   // bytes per XPT row (80 bf16 elems, no pad)
#define REG_SIZE   5120  // bytes per head ATT region (= 32*XPT_STRIDE)
#define REG_STRIDE 80    // bytes per ATT region row (40 bf16 elems, 32 used)
#define LDS_BYTES  40960 // 256 * 160 -> 4 WG/CU

__global__ void prep_weights_k(const float* __restrict__ Wi,
                               const float* __restrict__ Wo,
                               __bf16* __restrict__ WiT,
                               __bf16* __restrict__ WoT) {
    int n = blockIdx.x;   // 256
    int k = threadIdx.x;  // 256
    WiT[n * 256 + k] = (__bf16)Wi[k * 256 + n];   // WiT[n][k] = W_in[k][n]
    WoT[n * 256 + k] = (__bf16)Wo[k * 256 + n];   // WoT[e][c] = W_out[c][e]
}

__device__ __forceinline__ bf16x8 cvt8(f32x4 lo, f32x4 hi) {
    bf16x8 r;
    r[0] = (__bf16)lo.x; r[1] = (__bf16)lo.y; r[2] = (__bf16)lo.z; r[3] = (__bf16)lo.w;
    r[4] = (__bf16)hi.x; r[5] = (__bf16)hi.y; r[6] = (__bf16)hi.z; r[7] = (__bf16)hi.w;
    return r;
}

__global__ __launch_bounds__(256)
__attribute__((amdgpu_waves_per_eu(4, 4)))
void fused_attn_k(
    const float* __restrict__ x,     // (8,128,128,256) f32
    const float* __restrict__ aw,    // (8,8,256,64,80) f32
    const int*   __restrict__ idx,   // (8,256,16) i32
    const float* __restrict__ wts,   // (8,256,16) f32
    const float* __restrict__ b_in,  // (256) f32
    const float* __restrict__ b_out, // (256) f32
    const __bf16* __restrict__ WiT,  // (256,256) bf16 [n][k]
    const __bf16* __restrict__ WoT,  // (256,256) bf16 [e][c]
    float* __restrict__ out)         // (8,128,128,256) f32
{
    __shared__ __align__(16) unsigned char lds[LDS_BYTES];

    const int tid  = threadIdx.x;
    const int lane = tid & 63;
    const int wv   = tid >> 6;       // 0..3
    const int l16  = lane & 15;
    const int q    = lane >> 4;      // 0..3
    const int bid  = blockIdx.x;
    const int b    = bid >> 8;       // batch
    const int blk  = bid & 255;      // block id
    const int bh   = blk >> 4, bw = blk & 15;
    const int nbase = wv * 64;       // this wave's vd-column quarter

    const float* xb   = x   + (size_t)b * 16384 * 256;
    const int*   idxb = idx + (b * 256 + blk) * 16;
    const float* wtsb = wts + (b * 256 + blk) * 16;

    // =========== Phase 1: XPT[c][j] = (x_row_j . W_in[:,c] + b_in[c]) * rs ==
    // M = 80 tokens (5 m-tiles), N = 64 cols/wave (4 n-tiles), K = 256 (8 ch)
    for (int mt = 0; mt < 5; ++mt) {
        // A-operand row for this lane: token m = mt*16 + l16
        int m = mt * 16 + l16;
        int tokA;
        if (m < 64) {
            tokA = ((bh << 3) + (m >> 3)) * 128 + (bw << 3) + (m & 7);
        } else {
            tokA = idxb[m - 64];
        }
        const float* xrow = xb + (size_t)tokA * 256;
        bf16x8 af[8];
        #pragma unroll
        for (int kc = 0; kc < 8; ++kc) {
            const f32x4* p = (const f32x4*)(xrow + kc * 32 + q * 8);
            af[kc] = cvt8(p[0], p[1]);
        }
        // row scales for the 4 C-frag rows (gathered tokens get their weight)
        float rs[4];
        #pragma unroll
        for (int r = 0; r < 4; ++r) {
            int me = mt * 16 + q * 4 + r;
            rs[r] = (me >= 64) ? wtsb[me - 64] : 1.0f;
        }
        const int j0w = mt * 16 + q * 4;  // epilogue token base
        #pragma unroll
        for (int n4 = 0; n4 < 4; ++n4) {
            int c = nbase + n4 * 16 + l16;
            f32x4 acc = {0.f, 0.f, 0.f, 0.f};
            const __bf16* wcol = WiT + c * 256 + q * 8;
            #pragma unroll
            for (int kc = 0; kc < 8; ++kc) {
                bf16x8 bfrag = *(const bf16x8*)(wcol + kc * 32);
                acc = __builtin_amdgcn_mfma_f32_16x16x32_bf16(af[kc], bfrag, acc, 0, 0, 0);
            }
            float bias = b_in[c];
            bf16x4 w4;
            #pragma unroll
            for (int r = 0; r < 4; ++r)
                w4[r] = (__bf16)((acc[r] + bias) * rs[r]);
            // XPT[c][j0w .. j0w+3]
            *(bf16x4*)(lds + c * XPT_STRIDE + j0w * 2) = w4;
        }
    }

    // =========== Phase 2: attention, transposed: OUT^T[d][i] ================
    // per head: M = d (32, 2 tiles), N = i (64, 4 tiles), K = j (80, pad 96
    // via register-zeroed A-frags). Double-buffered aw prefetch over kc.
    #pragma unroll
    for (int hh = 0; hh < 2; ++hh) {
        const int h = wv * 2 + hh;
        const float* awh = aw + ((size_t)(h * 8 + b) * 256 + blk) * (64 * 80);
        const float* awl = awh + l16 * 80;    // this lane's base query row
        f32x4 acc[2][4];
        #pragma unroll
        for (int md = 0; md < 2; ++md)
            #pragma unroll
            for (int n4 = 0; n4 < 4; ++n4)
                acc[md][n4] = (f32x4){0.f, 0.f, 0.f, 0.f};

        // preload kc=0 B-chunks: aw[i][q*8 .. q*8+7] for i = n4*16 + l16
        f32x4 pb[4][2];
        #pragma unroll
        for (int n4 = 0; n4 < 4; ++n4) {
            const f32x4* p = (const f32x4*)(awl + n4 * (16 * 80) + q * 8);
            pb[n4][0] = p[0]; pb[n4][1] = p[1];
        }

        #pragma unroll
        for (int kc = 0; kc < 3; ++kc) {
            // prefetch next kc's B-chunks while this kc computes
            f32x4 nb[4][2];
            if (kc < 2) {
                int j0n = (kc + 1) * 32 + q * 8;
                int j0c = (j0n < 80) ? j0n : 0;   // clamp OOB lanes (A is 0)
                #pragma unroll
                for (int n4 = 0; n4 < 4; ++n4) {
                    const f32x4* p = (const f32x4*)(awl + n4 * (16 * 80) + j0c);
                    nb[n4][0] = p[0]; nb[n4][1] = p[1];
                }
            }
            // A-frags from XPT rows c = 32h + d (shared across n4)
            int j0  = kc * 32 + q * 8;
            int j0a = (j0 < 80) ? j0 : 0;
            bf16x8 a0 = *(const bf16x8*)(lds + (h * 32 + l16) * XPT_STRIDE + j0a * 2);
            bf16x8 a1 = *(const bf16x8*)(lds + (h * 32 + 16 + l16) * XPT_STRIDE + j0a * 2);
            if (j0 >= 80) {
                bf16x8 z = {};
                a0 = z; a1 = z;
            }
            #pragma unroll
            for (int n4 = 0; n4 < 4; ++n4) {
                bf16x8 bfrag = cvt8(pb[n4][0], pb[n4][1]);
                acc[0][n4] = __builtin_amdgcn_mfma_f32_16x16x32_bf16(a0, bfrag, acc[0][n4], 0, 0, 0);
                acc[1][n4] = __builtin_amdgcn_mfma_f32_16x16x32_bf16(a1, bfrag, acc[1][n4], 0, 0, 0);
            }
            if (kc < 2) {
                #pragma unroll
                for (int n4 = 0; n4 < 4; ++n4) {
                    pb[n4][0] = nb[n4][0]; pb[n4][1] = nb[n4][1];
                }
            }
        }

        // epilogue: ATT[i][c] for c-chunk of head h, into region(h) which
        // aliases this head's (already fully read) XPT rows.
        // C-frag: rows d = md*16 + q*4 + r, col i = n4*16 + l16.
        #pragma unroll
        for (int n4 = 0; n4 < 4; ++n4) {
            int i = n4 * 16 + l16;
            #pragma unroll
            for (int md = 0; md < 2; ++md) {
                bf16x4 w4;
                #pragma unroll
                for (int r = 0; r < 4; ++r)
                    w4[r] = (__bf16)acc[md][n4][r];
                int d0 = md * 16 + q * 4;
                *(bf16x4*)(lds + h * REG_SIZE + i * REG_STRIDE + d0 * 2) = w4;
            }
        }
    }

    __syncthreads();

    // =========== Phase 3: FIN[i][e] = ATT[i][:] @ W_out + b_out =============
    // M = 64 (4 m-tiles), N = 64 cols/wave (4 n-tiles), K = 256 (8 chunks,
    // chunk kc lives in head region kc).
    #pragma unroll
    for (int mt = 0; mt < 4; ++mt) {
        bf16x8 af[8];
        #pragma unroll
        for (int kc = 0; kc < 8; ++kc)
            af[kc] = *(const bf16x8*)(lds + kc * REG_SIZE +
                                      (mt * 16 + l16) * REG_STRIDE + q * 16);
        #pragma unroll
        for (int n4 = 0; n4 < 4; ++n4) {
            int e = nbase + n4 * 16 + l16;
            f32x4 acc = {0.f, 0.f, 0.f, 0.f};
            const __bf16* wcol = WoT + e * 256 + q * 8;
            #pragma unroll
            for (int kc = 0; kc < 8; ++kc) {
                bf16x8 bfrag = *(const bf16x8*)(wcol + kc * 32);
                acc = __builtin_amdgcn_mfma_f32_16x16x32_bf16(af[kc], bfrag, acc, 0, 0, 0);
            }
            float bias = b_out[e];
            #pragma unroll
            for (int r = 0; r < 4; ++r) {
                int ie  = mt * 16 + q * 4 + r;
                int tok = ((bh << 3) + (ie >> 3)) * 128 + (bw << 3) + (ie & 7);
                out[((size_t)b * 16384 + tok) * 256 + e] = acc[r] + bias;
            }
        }
    }
}

extern "C" void kernel_launch(void* const* d_in, const int* in_sizes, int n_in,
                              void* d_out, int out_size, void* d_ws, size_t ws_size,
                              hipStream_t stream) {
    (void)in_sizes; (void)n_in; (void)out_size; (void)ws_size;
    const float* x   = (const float*)d_in[0];
    const float* aw  = (const float*)d_in[1];
    const int*   idx = (const int*)d_in[2];
    const float* wts = (const float*)d_in[3];
    const float* Wi  = (const float*)d_in[4];
    const float* bi  = (const float*)d_in[5];
    const float* Wo  = (const float*)d_in[6];
    const float* bo  = (const float*)d_in[7];

    __bf16* WiT = (__bf16*)d_ws;          // 256*256 bf16 = 128 KB
    __bf16* WoT = WiT + 256 * 256;        // next 128 KB
    float*  o   = (float*)d_out;

    prep_weights_k<<<dim3(256), dim3(256), 0, stream>>>(Wi, Wo, WiT, WoT);
    fused_attn_k<<<dim3(2048), dim3(256), 0, stream>>>(
        x, aw, idx, wts, bi, bo, WiT, WoT, o);
}

// Round 3
// 753.630 us; speedup vs baseline: 1.0833x; 1.0833x over previous
//
#include <hip/hip_runtime.h>

// ---------------------------------------------------------------------------
// SelfAttention block-sparse value aggregation, fully fused, bf16 MFMA.
// B=8, H=W=128, E=256, VD=256, nh=8, vhd=32, bs=8 (bs2=64), topk=16.
// One workgroup (256 thr = 4 waves) per (batch, block) tile; 2048 WGs.
// R2: LDS 52KB->40KB (4 WG/CU), K-pad via register-zeroed A-frags,
//     phase-2 A-frag hoist + double-buffered aw prefetch, launch_bounds(256,4).
// R3/R4: amdgpu_waves_per_eu(4,4) on top of launch_bounds(256) -> ZERO effect
//     (VGPR_Count stayed 64, identical counters). WRITE excess (358 vs 134 MB
//     ideal) + 20x air between MFMA content and runtime still says scratch
//     spill round-trips in all three phases.
// R5: two levers, same register theory:
//     (a) respell the pin: drop __launch_bounds__, use
//         amdgpu_flat_work_group_size(256,256) + amdgpu_waves_per_eu(1,4)
//         (max=4 waves/EU is what sets the 128-VGPR budget; min=4 demand may
//         have been silently dropped).
//     (b) shrink phase-2 live set ~130 -> ~98: current aw operand held as
//         bf16x8 pbf[4] (16 regs, not 32 f32); only the in-flight prefetch nb
//         stays f32. cvt nb->pbf placed AFTER the MFMA cluster so the
//         prefetch waitcnt lands under compute. Numerics identical (same
//         RTN bf16 cast, just relocated).
// LDS: XPT[256 cols][80 tokens] bf16 (stride 160B); per-head ATT region
// (5120B, stride 80B) aliases exactly that head's 32 XPT rows, written by the
// same wave after its reads complete -> single __syncthreads() in kernel.
// ---------------------------------------------------------------------------

typedef __attribute__((ext_vector_type(4))) float   f32x4;
typedef __attribute__((ext_vector_type(8))) __bf16  bf16x8;
typedef __attribute__((ext_vector_type(4))) __bf16  bf16x4;

#define XPT_STRIDE 160   // bytes per XPT row (80 bf16 elems, no pad)
#define REG_SIZE   5120  // bytes per head ATT region (= 32*XPT_STRIDE)
#define REG_STRIDE 80    // bytes per ATT region row (40 bf16 elems, 32 used)
#define LDS_BYTES  40960 // 256 * 160 -> 4 WG/CU

__global__ void prep_weights_k(const float* __restrict__ Wi,
                               const float* __restrict__ Wo,
                               __bf16* __restrict__ WiT,
                               __bf16* __restrict__ WoT) {
    int n = blockIdx.x;   // 256
    int k = threadIdx.x;  // 256
    WiT[n * 256 + k] = (__bf16)Wi[k * 256 + n];   // WiT[n][k] = W_in[k][n]
    WoT[n * 256 + k] = (__bf16)Wo[k * 256 + n];   // WoT[e][c] = W_out[c][e]
}

__device__ __forceinline__ bf16x8 cvt8(f32x4 lo, f32x4 hi) {
    bf16x8 r;
    r[0] = (__bf16)lo.x; r[1] = (__bf16)lo.y; r[2] = (__bf16)lo.z; r[3] = (__bf16)lo.w;
    r[4] = (__bf16)hi.x; r[5] = (__bf16)hi.y; r[6] = (__bf16)hi.z; r[7] = (__bf16)hi.w;
    return r;
}

__global__
__attribute__((amdgpu_flat_work_group_size(256, 256), amdgpu_waves_per_eu(1, 4)))
void fused_attn_k(
    const float* __restrict__ x,     // (8,128,128,256) f32
    const float* __restrict__ aw,    // (8,8,256,64,80) f32
    const int*   __restrict__ idx,   // (8,256,16) i32
    const float* __restrict__ wts,   // (8,256,16) f32
    const float* __restrict__ b_in,  // (256) f32
    const float* __restrict__ b_out, // (256) f32
    const __bf16* __restrict__ WiT,  // (256,256) bf16 [n][k]
    const __bf16* __restrict__ WoT,  // (256,256) bf16 [e][c]
    float* __restrict__ out)         // (8,128,128,256) f32
{
    __shared__ __align__(16) unsigned char lds[LDS_BYTES];

    const int tid  = threadIdx.x;
    const int lane = tid & 63;
    const int wv   = tid >> 6;       // 0..3
    const int l16  = lane & 15;
    const int q    = lane >> 4;      // 0..3
    const int bid  = blockIdx.x;
    const int b    = bid >> 8;       // batch
    const int blk  = bid & 255;      // block id
    const int bh   = blk >> 4, bw = blk & 15;
    const int nbase = wv * 64;       // this wave's vd-column quarter

    const float* xb   = x   + (size_t)b * 16384 * 256;
    const int*   idxb = idx + (b * 256 + blk) * 16;
    const float* wtsb = wts + (b * 256 + blk) * 16;

    // =========== Phase 1: XPT[c][j] = (x_row_j . W_in[:,c] + b_in[c]) * rs ==
    // M = 80 tokens (5 m-tiles), N = 64 cols/wave (4 n-tiles), K = 256 (8 ch)
    for (int mt = 0; mt < 5; ++mt) {
        // A-operand row for this lane: token m = mt*16 + l16
        int m = mt * 16 + l16;
        int tokA;
        if (m < 64) {
            tokA = ((bh << 3) + (m >> 3)) * 128 + (bw << 3) + (m & 7);
        } else {
            tokA = idxb[m - 64];
        }
        const float* xrow = xb + (size_t)tokA * 256;
        bf16x8 af[8];
        #pragma unroll
        for (int kc = 0; kc < 8; ++kc) {
            const f32x4* p = (const f32x4*)(xrow + kc * 32 + q * 8);
            af[kc] = cvt8(p[0], p[1]);
        }
        // row scales for the 4 C-frag rows (gathered tokens get their weight)
        float rs[4];
        #pragma unroll
        for (int r = 0; r < 4; ++r) {
            int me = mt * 16 + q * 4 + r;
            rs[r] = (me >= 64) ? wtsb[me - 64] : 1.0f;
        }
        const int j0w = mt * 16 + q * 4;  // epilogue token base
        #pragma unroll
        for (int n4 = 0; n4 < 4; ++n4) {
            int c = nbase + n4 * 16 + l16;
            f32x4 acc = {0.f, 0.f, 0.f, 0.f};
            const __bf16* wcol = WiT + c * 256 + q * 8;
            #pragma unroll
            for (int kc = 0; kc < 8; ++kc) {
                bf16x8 bfrag = *(const bf16x8*)(wcol + kc * 32);
                acc = __builtin_amdgcn_mfma_f32_16x16x32_bf16(af[kc], bfrag, acc, 0, 0, 0);
            }
            float bias = b_in[c];
            bf16x4 w4;
            #pragma unroll
            for (int r = 0; r < 4; ++r)
                w4[r] = (__bf16)((acc[r] + bias) * rs[r]);
            // XPT[c][j0w .. j0w+3]
            *(bf16x4*)(lds + c * XPT_STRIDE + j0w * 2) = w4;
        }
    }

    // =========== Phase 2: attention, transposed: OUT^T[d][i] ================
    // per head: M = d (32, 2 tiles), N = i (64, 4 tiles), K = j (80, pad 96
    // via register-zeroed A-frags). Double-buffered aw prefetch over kc;
    // current operand lives as bf16 (16 regs), only the prefetch is f32.
    #pragma unroll
    for (int hh = 0; hh < 2; ++hh) {
        const int h = wv * 2 + hh;
        const float* awh = aw + ((size_t)(h * 8 + b) * 256 + blk) * (64 * 80);
        const float* awl = awh + l16 * 80;    // this lane's base query row
        f32x4 acc[2][4];
        #pragma unroll
        for (int md = 0; md < 2; ++md)
            #pragma unroll
            for (int n4 = 0; n4 < 4; ++n4)
                acc[md][n4] = (f32x4){0.f, 0.f, 0.f, 0.f};

        // preload kc=0 B-chunks and convert: aw[i][q*8..+7], i = n4*16+l16
        bf16x8 pbf[4];
        #pragma unroll
        for (int n4 = 0; n4 < 4; ++n4) {
            const f32x4* p = (const f32x4*)(awl + n4 * (16 * 80) + q * 8);
            pbf[n4] = cvt8(p[0], p[1]);
        }

        #pragma unroll
        for (int kc = 0; kc < 3; ++kc) {
            // prefetch next kc's B-chunks (f32, stays in flight over MFMAs)
            f32x4 nb[4][2];
            if (kc < 2) {
                int j0n = (kc + 1) * 32 + q * 8;
                int j0c = (j0n < 80) ? j0n : 0;   // clamp OOB lanes (A is 0)
                #pragma unroll
                for (int n4 = 0; n4 < 4; ++n4) {
                    const f32x4* p = (const f32x4*)(awl + n4 * (16 * 80) + j0c);
                    nb[n4][0] = p[0]; nb[n4][1] = p[1];
                }
            }
            // A-frags from XPT rows c = 32h + d (shared across n4)
            int j0  = kc * 32 + q * 8;
            int j0a = (j0 < 80) ? j0 : 0;
            bf16x8 a0 = *(const bf16x8*)(lds + (h * 32 + l16) * XPT_STRIDE + j0a * 2);
            bf16x8 a1 = *(const bf16x8*)(lds + (h * 32 + 16 + l16) * XPT_STRIDE + j0a * 2);
            if (j0 >= 80) {
                bf16x8 z = {};
                a0 = z; a1 = z;
            }
            #pragma unroll
            for (int n4 = 0; n4 < 4; ++n4) {
                acc[0][n4] = __builtin_amdgcn_mfma_f32_16x16x32_bf16(a0, pbf[n4], acc[0][n4], 0, 0, 0);
                acc[1][n4] = __builtin_amdgcn_mfma_f32_16x16x32_bf16(a1, pbf[n4], acc[1][n4], 0, 0, 0);
            }
            if (kc < 2) {
                // convert prefetch to bf16 current operand; the waitcnt for
                // nb lands here, after the MFMA cluster above has issued.
                #pragma unroll
                for (int n4 = 0; n4 < 4; ++n4)
                    pbf[n4] = cvt8(nb[n4][0], nb[n4][1]);
            }
        }

        // epilogue: ATT[i][c] for c-chunk of head h, into region(h) which
        // aliases this head's (already fully read) XPT rows.
        // C-frag: rows d = md*16 + q*4 + r, col i = n4*16 + l16.
        #pragma unroll
        for (int n4 = 0; n4 < 4; ++n4) {
            int i = n4 * 16 + l16;
            #pragma unroll
            for (int md = 0; md < 2; ++md) {
                bf16x4 w4;
                #pragma unroll
                for (int r = 0; r < 4; ++r)
                    w4[r] = (__bf16)acc[md][n4][r];
                int d0 = md * 16 + q * 4;
                *(bf16x4*)(lds + h * REG_SIZE + i * REG_STRIDE + d0 * 2) = w4;
            }
        }
    }

    __syncthreads();

    // =========== Phase 3: FIN[i][e] = ATT[i][:] @ W_out + b_out =============
    // M = 64 (4 m-tiles), N = 64 cols/wave (4 n-tiles), K = 256 (8 chunks,
    // chunk kc lives in head region kc).
    #pragma unroll
    for (int mt = 0; mt < 4; ++mt) {
        bf16x8 af[8];
        #pragma unroll
        for (int kc = 0; kc < 8; ++kc)
            af[kc] = *(const bf16x8*)(lds + kc * REG_SIZE +
                                      (mt * 16 + l16) * REG_STRIDE + q * 16);
        #pragma unroll
        for (int n4 = 0; n4 < 4; ++n4) {
            int e = nbase + n4 * 16 + l16;
            f32x4 acc = {0.f, 0.f, 0.f, 0.f};
            const __bf16* wcol = WoT + e * 256 + q * 8;
            #pragma unroll
            for (int kc = 0; kc < 8; ++kc) {
                bf16x8 bfrag = *(const bf16x8*)(wcol + kc * 32);
                acc = __builtin_amdgcn_mfma_f32_16x16x32_bf16(af[kc], bfrag, acc, 0, 0, 0);
            }
            float bias = b_out[e];
            #pragma unroll
            for (int r = 0; r < 4; ++r) {
                int ie  = mt * 16 + q * 4 + r;
                int tok = ((bh << 3) + (ie >> 3)) * 128 + (bw << 3) + (ie & 7);
                out[((size_t)b * 16384 + tok) * 256 + e] = acc[r] + bias;
            }
        }
    }
}

extern "C" void kernel_launch(void* const* d_in, const int* in_sizes, int n_in,
                              void* d_out, int out_size, void* d_ws, size_t ws_size,
                              hipStream_t stream) {
    (void)in_sizes; (void)n_in; (void)out_size; (void)ws_size;
    const float* x   = (const float*)d_in[0];
    const float* aw  = (const float*)d_in[1];
    const int*   idx = (const int*)d_in[2];
    const float* wts = (const float*)d_in[3];
    const float* Wi  = (const float*)d_in[4];
    const float* bi  = (const float*)d_in[5];
    const float* Wo  = (const float*)d_in[6];
    const float* bo  = (const float*)d_in[7];

    __bf16* WiT = (__bf16*)d_ws;          // 256*256 bf16 = 128 KB
    __bf16* WoT = WiT + 256 * 256;        // next 128 KB
    float*  o   = (float*)d_out;

    prep_weights_k<<<dim3(256), dim3(256), 0, stream>>>(Wi, Wo, WiT, WoT);
    fused_attn_k<<<dim3(2048), dim3(256), 0, stream>>>(
        x, aw, idx, wts, bi, bo, WiT, WoT, o);
}

// Round 4
// 705.033 us; speedup vs baseline: 1.1580x; 1.0689x over previous
//
#include <hip/hip_runtime.h>

// ---------------------------------------------------------------------------
// SelfAttention block-sparse value aggregation, fully fused, bf16 MFMA.
// B=8, H=W=128, E=256, VD=256, nh=8, vhd=32, bs=8 (bs2=64), topk=16.
// One workgroup (256 thr = 4 waves) per (batch, block) tile; 2048 WGs.
// R2: LDS 52KB->40KB (4 WG/CU), K-pad via register-zeroed A-frags.
// R5: amdgpu_flat_work_group_size + waves_per_eu(1,4) (NO launch_bounds)
//     unlocked 128 VGPR: spill writeback gone (WRITE 358->131MB = ideal),
//     420->354us. Counters still idle (Mfma 5%, HBM 14%): issue-starved on
//     dependent load chains (~45 latency round-trips/wave, 1 load/60cy/CU).
// R6: cut chains ~45 -> ~26 via ping-pong prefetch of B-fragment blocks:
//     phases 1 & 3 double-buffer the 8x bf16x8 WiT/WoT blocks across n4
//     (issue n4+1's 32-reg block before n4's MFMA cluster consumes its own),
//     hoist b_in/b_out loads. Live set ~114 regs < 128 budget.
// LDS: XPT[256 cols][80 tokens] bf16 (stride 160B); per-head ATT region
// (5120B, stride 80B) aliases exactly that head's 32 XPT rows, written by the
// same wave after its reads complete -> single __syncthreads() in kernel.
// ---------------------------------------------------------------------------

typedef __attribute__((ext_vector_type(4))) float   f32x4;
typedef __attribute__((ext_vector_type(8))) __bf16  bf16x8;
typedef __attribute__((ext_vector_type(4))) __bf16  bf16x4;

#define XPT_STRIDE 160   // bytes per XPT row (80 bf16 elems, no pad)
#define REG_SIZE   5120  // bytes per head ATT region (= 32*XPT_STRIDE)
#define REG_STRIDE 80    // bytes per ATT region row (40 bf16 elems, 32 used)
#define LDS_BYTES  40960 // 256 * 160 -> 4 WG/CU

__global__ void prep_weights_k(const float* __restrict__ Wi,
                               const float* __restrict__ Wo,
                               __bf16* __restrict__ WiT,
                               __bf16* __restrict__ WoT) {
    int n = blockIdx.x;   // 256
    int k = threadIdx.x;  // 256
    WiT[n * 256 + k] = (__bf16)Wi[k * 256 + n];   // WiT[n][k] = W_in[k][n]
    WoT[n * 256 + k] = (__bf16)Wo[k * 256 + n];   // WoT[e][c] = W_out[c][e]
}

__device__ __forceinline__ bf16x8 cvt8(f32x4 lo, f32x4 hi) {
    bf16x8 r;
    r[0] = (__bf16)lo.x; r[1] = (__bf16)lo.y; r[2] = (__bf16)lo.z; r[3] = (__bf16)lo.w;
    r[4] = (__bf16)hi.x; r[5] = (__bf16)hi.y; r[6] = (__bf16)hi.z; r[7] = (__bf16)hi.w;
    return r;
}

// load an 8-chunk B-fragment block (8 x 16B = 32 VGPRs) from a weight column
__device__ __forceinline__ void loadb8(bf16x8 (&bf)[8], const __bf16* base) {
    #pragma unroll
    for (int kc = 0; kc < 8; ++kc)
        bf[kc] = *(const bf16x8*)(base + kc * 32);
}

__global__
__attribute__((amdgpu_flat_work_group_size(256, 256), amdgpu_waves_per_eu(1, 4)))
void fused_attn_k(
    const float* __restrict__ x,     // (8,128,128,256) f32
    const float* __restrict__ aw,    // (8,8,256,64,80) f32
    const int*   __restrict__ idx,   // (8,256,16) i32
    const float* __restrict__ wts,   // (8,256,16) f32
    const float* __restrict__ b_in,  // (256) f32
    const float* __restrict__ b_out, // (256) f32
    const __bf16* __restrict__ WiT,  // (256,256) bf16 [n][k]
    const __bf16* __restrict__ WoT,  // (256,256) bf16 [e][c]
    float* __restrict__ out)         // (8,128,128,256) f32
{
    __shared__ __align__(16) unsigned char lds[LDS_BYTES];

    const int tid  = threadIdx.x;
    const int lane = tid & 63;
    const int wv   = tid >> 6;       // 0..3
    const int l16  = lane & 15;
    const int q    = lane >> 4;      // 0..3
    const int bid  = blockIdx.x;
    const int b    = bid >> 8;       // batch
    const int blk  = bid & 255;      // block id
    const int bh   = blk >> 4, bw = blk & 15;
    const int nbase = wv * 64;       // this wave's vd-column quarter

    const float* xb   = x   + (size_t)b * 16384 * 256;
    const int*   idxb = idx + (b * 256 + blk) * 16;
    const float* wtsb = wts + (b * 256 + blk) * 16;

    // =========== Phase 1: XPT[c][j] = (x_row_j . W_in[:,c] + b_in[c]) * rs ==
    // M = 80 tokens (5 m-tiles), N = 64 cols/wave (4 n-tiles), K = 256 (8 ch)
    // n4 ping-pong: WiT block for n4+1 in flight while n4's MFMAs run.
    float bi4[4];
    #pragma unroll
    for (int n4 = 0; n4 < 4; ++n4)
        bi4[n4] = b_in[nbase + n4 * 16 + l16];

    for (int mt = 0; mt < 5; ++mt) {
        // A-operand row for this lane: token m = mt*16 + l16
        int m = mt * 16 + l16;
        int tokA;
        if (m < 64) {
            tokA = ((bh << 3) + (m >> 3)) * 128 + (bw << 3) + (m & 7);
        } else {
            tokA = idxb[m - 64];
        }
        const float* xrow = xb + (size_t)tokA * 256;
        bf16x8 af[8];
        #pragma unroll
        for (int kc = 0; kc < 8; ++kc) {
            const f32x4* p = (const f32x4*)(xrow + kc * 32 + q * 8);
            af[kc] = cvt8(p[0], p[1]);
        }
        // row scales for the 4 C-frag rows (gathered tokens get their weight)
        float rs[4];
        #pragma unroll
        for (int r = 0; r < 4; ++r) {
            int me = mt * 16 + q * 4 + r;
            rs[r] = (me >= 64) ? wtsb[me - 64] : 1.0f;
        }
        const int j0w = mt * 16 + q * 4;  // epilogue token base

        const __bf16* wq = WiT + (nbase + l16) * 256 + q * 8;
        bf16x8 bA[8], bB[8];
        loadb8(bA, wq);                 // n4=0
        loadb8(bB, wq + 16 * 256);      // n4=1 (in flight over n4=0 compute)

        #pragma unroll
        for (int n4 = 0; n4 < 4; ++n4) {
            const bf16x8 (&bc)[8] = (n4 & 1) ? bB : bA;
            f32x4 acc = {0.f, 0.f, 0.f, 0.f};
            #pragma unroll
            for (int kc = 0; kc < 8; ++kc)
                acc = __builtin_amdgcn_mfma_f32_16x16x32_bf16(af[kc], bc[kc], acc, 0, 0, 0);
            // issue next-next block into the buffer just consumed
            if (n4 == 0) loadb8(bA, wq + 32 * 256);   // n4=2
            if (n4 == 1) loadb8(bB, wq + 48 * 256);   // n4=3
            int c = nbase + n4 * 16 + l16;
            bf16x4 w4;
            #pragma unroll
            for (int r = 0; r < 4; ++r)
                w4[r] = (__bf16)((acc[r] + bi4[n4]) * rs[r]);
            *(bf16x4*)(lds + c * XPT_STRIDE + j0w * 2) = w4;
        }
    }

    // =========== Phase 2: attention, transposed: OUT^T[d][i] ================
    // per head: M = d (32, 2 tiles), N = i (64, 4 tiles), K = j (80, pad 96
    // via register-zeroed A-frags). Double-buffered aw prefetch over kc;
    // current operand lives as bf16 (16 regs), only the prefetch is f32.
    #pragma unroll
    for (int hh = 0; hh < 2; ++hh) {
        const int h = wv * 2 + hh;
        const float* awh = aw + ((size_t)(h * 8 + b) * 256 + blk) * (64 * 80);
        const float* awl = awh + l16 * 80;    // this lane's base query row
        f32x4 acc[2][4];
        #pragma unroll
        for (int md = 0; md < 2; ++md)
            #pragma unroll
            for (int n4 = 0; n4 < 4; ++n4)
                acc[md][n4] = (f32x4){0.f, 0.f, 0.f, 0.f};

        // preload kc=0 B-chunks and convert: aw[i][q*8..+7], i = n4*16+l16
        bf16x8 pbf[4];
        #pragma unroll
        for (int n4 = 0; n4 < 4; ++n4) {
            const f32x4* p = (const f32x4*)(awl + n4 * (16 * 80) + q * 8);
            pbf[n4] = cvt8(p[0], p[1]);
        }

        #pragma unroll
        for (int kc = 0; kc < 3; ++kc) {
            // prefetch next kc's B-chunks (f32, stays in flight over MFMAs)
            f32x4 nb[4][2];
            if (kc < 2) {
                int j0n = (kc + 1) * 32 + q * 8;
                int j0c = (j0n < 80) ? j0n : 0;   // clamp OOB lanes (A is 0)
                #pragma unroll
                for (int n4 = 0; n4 < 4; ++n4) {
                    const f32x4* p = (const f32x4*)(awl + n4 * (16 * 80) + j0c);
                    nb[n4][0] = p[0]; nb[n4][1] = p[1];
                }
            }
            // A-frags from XPT rows c = 32h + d (shared across n4)
            int j0  = kc * 32 + q * 8;
            int j0a = (j0 < 80) ? j0 : 0;
            bf16x8 a0 = *(const bf16x8*)(lds + (h * 32 + l16) * XPT_STRIDE + j0a * 2);
            bf16x8 a1 = *(const bf16x8*)(lds + (h * 32 + 16 + l16) * XPT_STRIDE + j0a * 2);
            if (j0 >= 80) {
                bf16x8 z = {};
                a0 = z; a1 = z;
            }
            #pragma unroll
            for (int n4 = 0; n4 < 4; ++n4) {
                acc[0][n4] = __builtin_amdgcn_mfma_f32_16x16x32_bf16(a0, pbf[n4], acc[0][n4], 0, 0, 0);
                acc[1][n4] = __builtin_amdgcn_mfma_f32_16x16x32_bf16(a1, pbf[n4], acc[1][n4], 0, 0, 0);
            }
            if (kc < 2) {
                // convert prefetch to bf16 current operand; the waitcnt for
                // nb lands here, after the MFMA cluster above has issued.
                #pragma unroll
                for (int n4 = 0; n4 < 4; ++n4)
                    pbf[n4] = cvt8(nb[n4][0], nb[n4][1]);
            }
        }

        // epilogue: ATT[i][c] for c-chunk of head h, into region(h) which
        // aliases this head's (already fully read) XPT rows.
        // C-frag: rows d = md*16 + q*4 + r, col i = n4*16 + l16.
        #pragma unroll
        for (int n4 = 0; n4 < 4; ++n4) {
            int i = n4 * 16 + l16;
            #pragma unroll
            for (int md = 0; md < 2; ++md) {
                bf16x4 w4;
                #pragma unroll
                for (int r = 0; r < 4; ++r)
                    w4[r] = (__bf16)acc[md][n4][r];
                int d0 = md * 16 + q * 4;
                *(bf16x4*)(lds + h * REG_SIZE + i * REG_STRIDE + d0 * 2) = w4;
            }
        }
    }

    __syncthreads();

    // =========== Phase 3: FIN[i][e] = ATT[i][:] @ W_out + b_out =============
    // M = 64 (4 m-tiles), N = 64 cols/wave (4 n-tiles), K = 256 (8 chunks,
    // chunk kc lives in head region kc). n4 ping-pong on WoT blocks.
    float bo4[4];
    #pragma unroll
    for (int n4 = 0; n4 < 4; ++n4)
        bo4[n4] = b_out[nbase + n4 * 16 + l16];

    #pragma unroll
    for (int mt = 0; mt < 4; ++mt) {
        bf16x8 af[8];
        #pragma unroll
        for (int kc = 0; kc < 8; ++kc)
            af[kc] = *(const bf16x8*)(lds + kc * REG_SIZE +
                                      (mt * 16 + l16) * REG_STRIDE + q * 16);

        const __bf16* wq = WoT + (nbase + l16) * 256 + q * 8;
        bf16x8 bA[8], bB[8];
        loadb8(bA, wq);                 // n4=0
        loadb8(bB, wq + 16 * 256);      // n4=1

        #pragma unroll
        for (int n4 = 0; n4 < 4; ++n4) {
            const bf16x8 (&bc)[8] = (n4 & 1) ? bB : bA;
            f32x4 acc = {0.f, 0.f, 0.f, 0.f};
            #pragma unroll
            for (int kc = 0; kc < 8; ++kc)
                acc = __builtin_amdgcn_mfma_f32_16x16x32_bf16(af[kc], bc[kc], acc, 0, 0, 0);
            if (n4 == 0) loadb8(bA, wq + 32 * 256);   // n4=2
            if (n4 == 1) loadb8(bB, wq + 48 * 256);   // n4=3
            int e = nbase + n4 * 16 + l16;
            #pragma unroll
            for (int r = 0; r < 4; ++r) {
                int ie  = mt * 16 + q * 4 + r;
                int tok = ((bh << 3) + (ie >> 3)) * 128 + (bw << 3) + (ie & 7);
                out[((size_t)b * 16384 + tok) * 256 + e] = acc[r] + bo4[n4];
            }
        }
    }
}

extern "C" void kernel_launch(void* const* d_in, const int* in_sizes, int n_in,
                              void* d_out, int out_size, void* d_ws, size_t ws_size,
                              hipStream_t stream) {
    (void)in_sizes; (void)n_in; (void)out_size; (void)ws_size;
    const float* x   = (const float*)d_in[0];
    const float* aw  = (const float*)d_in[1];
    const int*   idx = (const int*)d_in[2];
    const float* wts = (const float*)d_in[3];
    const float* Wi  = (const float*)d_in[4];
    const float* bi  = (const float*)d_in[5];
    const float* Wo  = (const float*)d_in[6];
    const float* bo  = (const float*)d_in[7];

    __bf16* WiT = (__bf16*)d_ws;          // 256*256 bf16 = 128 KB
    __bf16* WoT = WiT + 256 * 256;        // next 128 KB
    float*  o   = (float*)d_out;

    prep_weights_k<<<dim3(256), dim3(256), 0, stream>>>(Wi, Wo, WiT, WoT);
    fused_attn_k<<<dim3(2048), dim3(256), 0, stream>>>(
        x, aw, idx, wts, bi, bo, WiT, WoT, o);
}

// Round 5
// 614.830 us; speedup vs baseline: 1.3279x; 1.1467x over previous
//
#include <hip/hip_runtime.h>

// ---------------------------------------------------------------------------
// SelfAttention block-sparse value aggregation, fully fused, bf16 MFMA.
// B=8, H=W=128, E=256, VD=256, nh=8, vhd=32, bs=8 (bs2=64), topk=16.
// One workgroup (256 thr = 4 waves) per (batch, block) tile; 2048 WGs.
// R5: waves_per_eu attr unlocked 128 VGPR: spills gone, 420->354us.
// R6: n4 ping-pong prefetch of weight blocks: 354->310us. Counters still
//     idle (Mfma 5.7%, HBM 16%, Occ 22%) -> re-derived cost from TRAFFIC:
//     phase1 re-reads WiT 5x (640KB/WG), phase3 re-reads WoT 4x (512KB/WG)
//     => 2.9GB L2 traffic/kernel, ~3x the 84us L2-BW floor = the ~250us of
//     non-HBM time. aw HBM stream (63us floor) is only ~20% of kernel.
// R7: loop inversion + LDS x-staging to make weights single-read:
//     - stage x-tile (80 rows x 256ch) as bf16 into XB in LDS (coalesced
//       cooperative load; kills the 20 scattered per-wave gather steps),
//       in 2 parts (48+32 rows) so LDS total = 24576+40960 = 64KB exact.
//     - P1: n4-outer/mt-inner, WiT block loaded once per (n4, part): WiT
//       traffic 640KB -> 256KB/WG. af read from XB (XOR-swizzled, 2-way max).
//     - P3: n4-outer/mt-inner, WoT 512KB -> 128KB/WG (af already in LDS).
//     - 2 WG/CU (LDS 64KB); measured avg residency was 1.8 anyway. Relax to
//       waves_per_eu(1,2) (256-VGPR budget; occupancy is LDS-capped).
// LDS: XB[48|32 rows][512B] swizzled at [0,24576); XPT[256 c][160B] at
// [24576, 65536). Per-head ATT region (5120B) aliases its head's 32 XPT rows
// (wave-local P1/P2 -> no sync needed between P1 and P2).
// ---------------------------------------------------------------------------

typedef __attribute__((ext_vector_type(4))) float   f32x4;
typedef __attribute__((ext_vector_type(8))) __bf16  bf16x8;
typedef __attribute__((ext_vector_type(4))) __bf16  bf16x4;

#define XB_STRIDE  512    // bytes per XB row (256 bf16)
#define XPT_BASE   24576  // XB region size (48 rows * 512B)
#define XPT_STRIDE 160    // bytes per XPT row (80 bf16 elems)
#define REG_SIZE   5120   // bytes per head ATT region (= 32*XPT_STRIDE)
#define REG_STRIDE 80     // bytes per ATT region row (40 bf16, 32 used)
#define LDS_BYTES  65536  // 24576 + 40960 -> 2 WG/CU

__global__ void prep_weights_k(const float* __restrict__ Wi,
                               const float* __restrict__ Wo,
                               __bf16* __restrict__ WiT,
                               __bf16* __restrict__ WoT) {
    int n = blockIdx.x;   // 256
    int k = threadIdx.x;  // 256
    WiT[n * 256 + k] = (__bf16)Wi[k * 256 + n];   // WiT[n][k] = W_in[k][n]
    WoT[n * 256 + k] = (__bf16)Wo[k * 256 + n];   // WoT[e][c] = W_out[c][e]
}

__device__ __forceinline__ bf16x8 cvt8(f32x4 lo, f32x4 hi) {
    bf16x8 r;
    r[0] = (__bf16)lo.x; r[1] = (__bf16)lo.y; r[2] = (__bf16)lo.z; r[3] = (__bf16)lo.w;
    r[4] = (__bf16)hi.x; r[5] = (__bf16)hi.y; r[6] = (__bf16)hi.z; r[7] = (__bf16)hi.w;
    return r;
}

// load an 8-chunk B-fragment block (8 x 16B = 32 VGPRs) from a weight column
__device__ __forceinline__ void loadb8(bf16x8 (&bf)[8], const __bf16* base) {
    #pragma unroll
    for (int kc = 0; kc < 8; ++kc)
        bf[kc] = *(const bf16x8*)(base + kc * 32);
}

// Cooperative stage of x rows [r0, r0+nr) into XB (bf16, XOR-swizzled).
// Each 16-thread group handles one row; thread covers 16 ch (64B) -> 2 b128
// LDS writes. Swizzle: 16B-granular inner offset XORed with (row&7)<<4.
__device__ __forceinline__ void stage_xb(unsigned char* lds, const float* xb,
                                         const int* __restrict__ idxb,
                                         int tid, int bh, int bw,
                                         int r0, int nr) {
    for (int rr = 0; rr < (nr >> 4); ++rr) {
        int j  = r0 + rr * 16 + (tid >> 4);   // token row 0..79
        int jl = j - r0;                      // local XB row
        int tokA = (j < 64)
            ? (((bh << 3) + (j >> 3)) * 128 + (bw << 3) + (j & 7))
            : idxb[j - 64];
        const f32x4* v = (const f32x4*)(xb + (size_t)tokA * 256 + (tid & 15) * 16);
        f32x4 v0 = v[0], v1 = v[1], v2 = v[2], v3 = v[3];
        bf16x8 w0 = cvt8(v0, v1), w1 = cvt8(v2, v3);
        int inner = (tid & 15) * 32;
        int sw = (jl & 7) << 4;
        unsigned char* base = lds + jl * XB_STRIDE;
        *(bf16x8*)(base + (inner ^ sw))        = w0;
        *(bf16x8*)(base + ((inner + 16) ^ sw)) = w1;
    }
}

__global__
__attribute__((amdgpu_flat_work_group_size(256, 256), amdgpu_waves_per_eu(1, 2)))
void fused_attn_k(
    const float* __restrict__ x,     // (8,128,128,256) f32
    const float* __restrict__ aw,    // (8,8,256,64,80) f32
    const int*   __restrict__ idx,   // (8,256,16) i32
    const float* __restrict__ wts,   // (8,256,16) f32
    const float* __restrict__ b_in,  // (256) f32
    const float* __restrict__ b_out, // (256) f32
    const __bf16* __restrict__ WiT,  // (256,256) bf16 [n][k]
    const __bf16* __restrict__ WoT,  // (256,256) bf16 [e][c]
    float* __restrict__ out)         // (8,128,128,256) f32
{
    __shared__ __align__(16) unsigned char lds[LDS_BYTES];

    const int tid  = threadIdx.x;
    const int lane = tid & 63;
    const int wv   = tid >> 6;       // 0..3
    const int l16  = lane & 15;
    const int q    = lane >> 4;      // 0..3
    const int bid  = blockIdx.x;
    const int b    = bid >> 8;       // batch
    const int blk  = bid & 255;      // block id
    const int bh   = blk >> 4, bw = blk & 15;
    const int nbase = wv * 64;       // this wave's vd-column quarter

    const float* xb   = x   + (size_t)b * 16384 * 256;
    const int*   idxb = idx + (b * 256 + blk) * 16;
    const float* wtsb = wts + (b * 256 + blk) * 16;

    // =========== Phase 1: XPT[c][j] = (x_row_j . W_in[:,c] + b_in[c]) * rs ==
    // Two parts: stage XB rows [0,48) -> mt 0..2; rows [48,80) -> mt 3..4.
    // n4-outer / mt-inner: WiT block loaded ONCE per (part, n4).
    float bi4[4];
    #pragma unroll
    for (int n4 = 0; n4 < 4; ++n4)
        bi4[n4] = b_in[nbase + n4 * 16 + l16];

    for (int part = 0; part < 2; ++part) {
        const int r0  = part ? 48 : 0;
        const int nr  = part ? 32 : 48;
        const int mt0 = part ? 3 : 0;
        const int mtN = part ? 5 : 3;

        stage_xb(lds, xb, idxb, tid, bh, bw, r0, nr);
        __syncthreads();

        for (int n4 = 0; n4 < 4; ++n4) {
            const __bf16* wq = WiT + (nbase + n4 * 16 + l16) * 256 + q * 8;
            bf16x8 bb[8];
            loadb8(bb, wq);
            const int c = nbase + n4 * 16 + l16;

            for (int mt = mt0; mt < mtN; ++mt) {
                int ml = mt * 16 + l16 - r0;   // local XB row
                int sw = (ml & 7) << 4;
                bf16x8 af[8];
                #pragma unroll
                for (int kc = 0; kc < 8; ++kc)
                    af[kc] = *(const bf16x8*)(lds + ml * XB_STRIDE +
                                              ((kc * 64 + q * 16) ^ sw));
                f32x4 acc = {0.f, 0.f, 0.f, 0.f};
                #pragma unroll
                for (int kc = 0; kc < 8; ++kc)
                    acc = __builtin_amdgcn_mfma_f32_16x16x32_bf16(af[kc], bb[kc], acc, 0, 0, 0);
                // row scales (gathered tokens get their weight)
                float rs[4];
                #pragma unroll
                for (int r = 0; r < 4; ++r) {
                    int me = mt * 16 + q * 4 + r;
                    rs[r] = (me >= 64) ? wtsb[me - 64] : 1.0f;
                }
                int j0w = mt * 16 + q * 4;
                bf16x4 w4;
                #pragma unroll
                for (int r = 0; r < 4; ++r)
                    w4[r] = (__bf16)((acc[r] + bi4[n4]) * rs[r]);
                *(bf16x4*)(lds + XPT_BASE + c * XPT_STRIDE + j0w * 2) = w4;
            }
        }
        if (part == 0) __syncthreads();  // all waves done with XB before restage
    }

    // =========== Phase 2: attention, transposed: OUT^T[d][i] ================
    // per head: M = d (32, 2 tiles), N = i (64, 4 tiles), K = j (80, pad 96
    // via register-zeroed A-frags). Double-buffered aw prefetch over kc;
    // current operand lives as bf16 (16 regs), only the prefetch is f32.
    // Wave-local in LDS: reads its own XPT quarter, writes its ATT regions.
    #pragma unroll
    for (int hh = 0; hh < 2; ++hh) {
        const int h = wv * 2 + hh;
        const float* awh = aw + ((size_t)(h * 8 + b) * 256 + blk) * (64 * 80);
        const float* awl = awh + l16 * 80;    // this lane's base query row
        f32x4 acc[2][4];
        #pragma unroll
        for (int md = 0; md < 2; ++md)
            #pragma unroll
            for (int n4 = 0; n4 < 4; ++n4)
                acc[md][n4] = (f32x4){0.f, 0.f, 0.f, 0.f};

        // preload kc=0 B-chunks and convert: aw[i][q*8..+7], i = n4*16+l16
        bf16x8 pbf[4];
        #pragma unroll
        for (int n4 = 0; n4 < 4; ++n4) {
            const f32x4* p = (const f32x4*)(awl + n4 * (16 * 80) + q * 8);
            pbf[n4] = cvt8(p[0], p[1]);
        }

        #pragma unroll
        for (int kc = 0; kc < 3; ++kc) {
            // prefetch next kc's B-chunks (f32, stays in flight over MFMAs)
            f32x4 nb[4][2];
            if (kc < 2) {
                int j0n = (kc + 1) * 32 + q * 8;
                int j0c = (j0n < 80) ? j0n : 0;   // clamp OOB lanes (A is 0)
                #pragma unroll
                for (int n4 = 0; n4 < 4; ++n4) {
                    const f32x4* p = (const f32x4*)(awl + n4 * (16 * 80) + j0c);
                    nb[n4][0] = p[0]; nb[n4][1] = p[1];
                }
            }
            // A-frags from XPT rows c = 32h + d (shared across n4)
            int j0  = kc * 32 + q * 8;
            int j0a = (j0 < 80) ? j0 : 0;
            bf16x8 a0 = *(const bf16x8*)(lds + XPT_BASE + (h * 32 + l16) * XPT_STRIDE + j0a * 2);
            bf16x8 a1 = *(const bf16x8*)(lds + XPT_BASE + (h * 32 + 16 + l16) * XPT_STRIDE + j0a * 2);
            if (j0 >= 80) {
                bf16x8 z = {};
                a0 = z; a1 = z;
            }
            #pragma unroll
            for (int n4 = 0; n4 < 4; ++n4) {
                acc[0][n4] = __builtin_amdgcn_mfma_f32_16x16x32_bf16(a0, pbf[n4], acc[0][n4], 0, 0, 0);
                acc[1][n4] = __builtin_amdgcn_mfma_f32_16x16x32_bf16(a1, pbf[n4], acc[1][n4], 0, 0, 0);
            }
            if (kc < 2) {
                // convert prefetch to bf16 current operand; the waitcnt for
                // nb lands here, after the MFMA cluster above has issued.
                #pragma unroll
                for (int n4 = 0; n4 < 4; ++n4)
                    pbf[n4] = cvt8(nb[n4][0], nb[n4][1]);
            }
        }

        // epilogue: ATT[i][c] for c-chunk of head h, into region(h) which
        // aliases this head's (already fully read) XPT rows.
        // C-frag: rows d = md*16 + q*4 + r, col i = n4*16 + l16.
        #pragma unroll
        for (int n4 = 0; n4 < 4; ++n4) {
            int i = n4 * 16 + l16;
            #pragma unroll
            for (int md = 0; md < 2; ++md) {
                bf16x4 w4;
                #pragma unroll
                for (int r = 0; r < 4; ++r)
                    w4[r] = (__bf16)acc[md][n4][r];
                int d0 = md * 16 + q * 4;
                *(bf16x4*)(lds + XPT_BASE + h * REG_SIZE + i * REG_STRIDE + d0 * 2) = w4;
            }
        }
    }

    __syncthreads();

    // =========== Phase 3: FIN[i][e] = ATT[i][:] @ W_out + b_out =============
    // n4-outer / mt-inner: WoT block loaded ONCE per n4 (af is in LDS, cheap
    // to reload per mt). K = 256 (8 chunks, chunk kc lives in head region kc).
    #pragma unroll
    for (int n4 = 0; n4 < 4; ++n4) {
        const int e = nbase + n4 * 16 + l16;
        const __bf16* wq = WoT + e * 256 + q * 8;
        bf16x8 bb[8];
        loadb8(bb, wq);
        const float bo = b_out[e];

        #pragma unroll
        for (int mt = 0; mt < 4; ++mt) {
            bf16x8 af[8];
            #pragma unroll
            for (int kc = 0; kc < 8; ++kc)
                af[kc] = *(const bf16x8*)(lds + XPT_BASE + kc * REG_SIZE +
                                          (mt * 16 + l16) * REG_STRIDE + q * 16);
            f32x4 acc = {0.f, 0.f, 0.f, 0.f};
            #pragma unroll
            for (int kc = 0; kc < 8; ++kc)
                acc = __builtin_amdgcn_mfma_f32_16x16x32_bf16(af[kc], bb[kc], acc, 0, 0, 0);
            #pragma unroll
            for (int r = 0; r < 4; ++r) {
                int ie  = mt * 16 + q * 4 + r;
                int tok = ((bh << 3) + (ie >> 3)) * 128 + (bw << 3) + (ie & 7);
                out[((size_t)b * 16384 + tok) * 256 + e] = acc[r] + bo;
            }
        }
    }
}

extern "C" void kernel_launch(void* const* d_in, const int* in_sizes, int n_in,
                              void* d_out, int out_size, void* d_ws, size_t ws_size,
                              hipStream_t stream) {
    (void)in_sizes; (void)n_in; (void)out_size; (void)ws_size;
    const float* x   = (const float*)d_in[0];
    const float* aw  = (const float*)d_in[1];
    const int*   idx = (const int*)d_in[2];
    const float* wts = (const float*)d_in[3];
    const float* Wi  = (const float*)d_in[4];
    const float* bi  = (const float*)d_in[5];
    const float* Wo  = (const float*)d_in[6];
    const float* bo  = (const float*)d_in[7];

    __bf16* WiT = (__bf16*)d_ws;          // 256*256 bf16 = 128 KB
    __bf16* WoT = WiT + 256 * 256;        // next 128 KB
    float*  o   = (float*)d_out;

    prep_weights_k<<<dim3(256), dim3(256), 0, stream>>>(Wi, Wo, WiT, WoT);
    fused_attn_k<<<dim3(2048), dim3(256), 0, stream>>>(
        x, aw, idx, wts, bi, bo, WiT, WoT, o);
}